// Round 12
// baseline (423.052 us; speedup 1.0000x reference)
//
#include <hip/hip_runtime.h>
#include <hip/hip_bf16.h>
#include <math.h>

#define D_MODEL 2048
#define D_INNER 4096
#define D_STATE 16
#define D_CONV  4
#define DT_RANK 128
#define NB      2
#define TT      1024
#define M_TOT   (NB * TT)          // 2048 rows for all GEMMs
#define NC      16                 // scan chunks
#define CL      64                 // chunk length (TT/NC)
#define TC      16                 // conv t-chunk

typedef __bf16 bf16x8_t __attribute__((ext_vector_type(8)));
typedef __bf16 bf16x4_t __attribute__((ext_vector_type(4)));
typedef float  f32x4_t  __attribute__((ext_vector_type(4)));

// ---------------------------------------------------------------------------
// Fused cast/zero kernel (unchanged).
// ---------------------------------------------------------------------------
__global__ __launch_bounds__(256) void fused_cast(
    const float* __restrict__ x,  const float* __restrict__ wi,
    const float* __restrict__ wo, const float* __restrict__ wx,
    const float* __restrict__ wdt,
    __bf16* __restrict__ x16,  __bf16* __restrict__ wi16,
    __bf16* __restrict__ wo16, __bf16* __restrict__ wx16,
    __bf16* __restrict__ wdt16, __bf16* __restrict__ dbc16)
{
    const size_t g = (size_t)blockIdx.x * 256 + threadIdx.x;
    const float* src; __bf16* dst; size_t off;
    if      (g < 524288)  { src = x;   dst = x16;   off = g; }
    else if (g < 2621440) { src = wi;  dst = wi16;  off = g - 524288; }
    else if (g < 3670016) { src = wo;  dst = wo16;  off = g - 2621440; }
    else if (g < 3801088) { off = g - 3670016; dst = wx16;
                            src = (g < 3751936) ? wx : nullptr; }
    else if (g < 3866624) { src = wdt; dst = wdt16; off = g - 3801088; }
    else                  { src = nullptr; dst = dbc16; off = g - 3866624; }

    bf16x8_t v;
    if (src) {
        const float4 f0 = ((const float4*)src)[2 * off];
        const float4 f1 = ((const float4*)src)[2 * off + 1];
        v[0] = (__bf16)f0.x; v[1] = (__bf16)f0.y; v[2] = (__bf16)f0.z; v[3] = (__bf16)f0.w;
        v[4] = (__bf16)f1.x; v[5] = (__bf16)f1.y; v[6] = (__bf16)f1.z; v[7] = (__bf16)f1.w;
    } else {
        v = (bf16x8_t)(__bf16)0.f;   // bit pattern 0 == fp32 0.0 for zeroed fp32 dst
    }
    ((bf16x8_t*)dst)[off] = v;
}

// ---------------------------------------------------------------------------
// out = P0 + P1 elementwise (split-K reduction, fp32, float4-vectorized).
// ---------------------------------------------------------------------------
__global__ __launch_bounds__(256) void reduce_out(
    const float4* __restrict__ p0, const float4* __restrict__ p1,
    float4* __restrict__ o)
{
    const size_t g = (size_t)blockIdx.x * 256 + threadIdx.x;
    const float4 a = p0[g];
    const float4 b = p1[g];
    o[g] = make_float4(a.x + b.x, a.y + b.y, a.z + b.z, a.w + b.w);
}

// ---------------------------------------------------------------------------
// 256x256-tile bf16 MFMA GEMM, 512 threads (8 waves as 2M x 4N), BK=32,
// 4-deep LDS ring buffer, counted-vmcnt pipeline, setprio around MFMA,
// XOR slot-swizzled LDS.  R7-proven schedule (76.5 us, 0 bank conflicts).
// Structural ceiling accepted (R8/R9 variants null).
// C = A(M,K;lda) @ W(N,K;ldw)^T, bf16 out.  Requires K % 32 == 0.
// ---------------------------------------------------------------------------
__global__ __launch_bounds__(512, 2) void gemm_bf16_256(
    const __bf16* __restrict__ A, int lda,
    const __bf16* __restrict__ W, int ldw,
    __bf16* __restrict__ C, int ldc,
    int nt)                              // number of BK=32 K-tiles
{
    __shared__ __bf16 As[4 * 128 * 64];
    __shared__ __bf16 Bs[4 * 128 * 64];

    const int tid = threadIdx.x;
    const int w   = tid >> 6;
    const int l   = tid & 63;
    const int m0  = blockIdx.y * 256;
    const int n0  = blockIdx.x * 256;
    const int wm  = (w >> 2) * 128;      // wave M offset
    const int wn  = (w & 3) * 64;        // wave N offset

    const int sl   = ((l & 7) ^ (l >> 3)) & 7;
    const int srow = 2 * (w * 16 + (l >> 3)) + (sl >> 2);
    const int scol = (sl & 3) * 8;
    const __bf16* gA = A + (size_t)(m0 + srow) * lda + scol;
    const __bf16* gB = W + (size_t)(n0 + srow) * ldw + scol;
    __bf16* lA = &As[(size_t)w * 1024];  // wave-uniform LDS bases (elems)
    __bf16* lB = &Bs[(size_t)w * 1024];

    const int fr  = l & 15;
    const int swz = ((((fr & 1) * 4) + (l >> 4)) ^ ((fr >> 1) & 7)) * 8;
    const int aoff = wm * 32 + (fr >> 1) * 64 + swz;
    const int boff = wn * 32 + (fr >> 1) * 64 + swz;

    f32x4_t acc[8][4] = {};

#define STAGE_A(t, q) { \
    const __bf16* s0_ = gA + (size_t)(t) * 32; \
    __builtin_amdgcn_global_load_lds((const __attribute__((address_space(1))) void*)s0_, \
        (__attribute__((address_space(3))) void*)(lA + (q) * 8192), 16, 0, 0); \
    __builtin_amdgcn_global_load_lds((const __attribute__((address_space(1))) void*)(s0_ + (size_t)16 * lda), \
        (__attribute__((address_space(3))) void*)(lA + (q) * 8192 + 512), 16, 0, 0); }
#define STAGE_B(t, q) { \
    const __bf16* s0_ = gB + (size_t)(t) * 32; \
    __builtin_amdgcn_global_load_lds((const __attribute__((address_space(1))) void*)s0_, \
        (__attribute__((address_space(3))) void*)(lB + (q) * 8192), 16, 0, 0); \
    __builtin_amdgcn_global_load_lds((const __attribute__((address_space(1))) void*)(s0_ + (size_t)16 * ldw), \
        (__attribute__((address_space(3))) void*)(lB + (q) * 8192 + 512), 16, 0, 0); }

    STAGE_A(0, 0); STAGE_B(0, 0);
    STAGE_A(1, 1); STAGE_B(1, 1);
    asm volatile("s_waitcnt vmcnt(4)" ::: "memory");
    __builtin_amdgcn_s_barrier();

    for (int t = 0; t < nt; ++t) {
        const int q  = t & 3;
        const int qn = (t + 2) & 3;
        const __bf16* Aq = &As[q * 8192];
        const __bf16* Bq = &Bs[q * 8192];
        bf16x8_t av[4], bv[4];

#pragma unroll
        for (int i = 0; i < 4; i++)
            av[i] = *(const bf16x8_t*)&Aq[aoff + i * 512];
#pragma unroll
        for (int i = 0; i < 4; i++)
            bv[i] = *(const bf16x8_t*)&Bq[boff + i * 512];
        if (t + 2 < nt) STAGE_A(t + 2, qn);
        __builtin_amdgcn_s_barrier();
        asm volatile("s_waitcnt lgkmcnt(0)" ::: "memory");
        __builtin_amdgcn_sched_barrier(0);
        __builtin_amdgcn_s_setprio(1);
#pragma unroll
        for (int mt = 0; mt < 4; mt++)
#pragma unroll
            for (int nn = 0; nn < 4; nn++)
                acc[mt][nn] = __builtin_amdgcn_mfma_f32_16x16x32_bf16(
                    av[mt], bv[nn], acc[mt][nn], 0, 0, 0);
        __builtin_amdgcn_s_setprio(0);
        __builtin_amdgcn_s_barrier();

#pragma unroll
        for (int i = 0; i < 4; i++)
            av[i] = *(const bf16x8_t*)&Aq[aoff + (i + 4) * 512];
        if (t + 2 < nt) STAGE_B(t + 2, qn);
        __builtin_amdgcn_s_barrier();
        asm volatile("s_waitcnt lgkmcnt(0)" ::: "memory");
        __builtin_amdgcn_sched_barrier(0);
        __builtin_amdgcn_s_setprio(1);
#pragma unroll
        for (int mt = 0; mt < 4; mt++)
#pragma unroll
            for (int nn = 0; nn < 4; nn++)
                acc[mt + 4][nn] = __builtin_amdgcn_mfma_f32_16x16x32_bf16(
                    av[mt], bv[nn], acc[mt + 4][nn], 0, 0, 0);
        __builtin_amdgcn_s_setprio(0);
        if (t + 2 < nt) asm volatile("s_waitcnt vmcnt(4)" ::: "memory");
        else            asm volatile("s_waitcnt vmcnt(0)" ::: "memory");
        __builtin_amdgcn_s_barrier();
    }
#undef STAGE_A
#undef STAGE_B

    const int cn = n0 + wn + fr;
    const int rb = m0 + wm + (l >> 4) * 4;
#pragma unroll
    for (int mt = 0; mt < 8; mt++)
#pragma unroll
        for (int nn = 0; nn < 4; nn++)
#pragma unroll
            for (int r = 0; r < 4; r++)
                C[(size_t)(rb + mt * 16 + r) * ldc + cn + nn * 16] =
                    (__bf16)acc[mt][nn][r];
}

// ---------------------------------------------------------------------------
// bf16 MFMA GEMM: C(M,Nmax) OutT (+EPI) = A(M,K;lda) bf16 @ W(N,K;ldw)^T.
// 128x128 tile, 256 threads (4 waves).  Split-K via gridDim.z; czoff = per-z
// C offset (0 -> same C + EPI=2 atomics; >0 -> disjoint partials + EPI=0).
// ---------------------------------------------------------------------------
template <int EPI, int KSTEP, typename OutT>
__global__ __launch_bounds__(256) void gemm_bf16_nt(
    const __bf16* __restrict__ A, int lda,
    const __bf16* __restrict__ W, int ldw,
    OutT* __restrict__ C, int ldc,
    int Kloop, int Nmax, const float* __restrict__ bias, size_t czoff)
{
    __shared__ __bf16 As[128 * KSTEP];
    __shared__ __bf16 Bs[128 * KSTEP];

    const int tid  = threadIdx.x;
    const int wave = tid >> 6;
    const int lane = tid & 63;
    const int m0 = blockIdx.y * 128;
    const int n0 = blockIdx.x * 128;
    const int mw = (wave >> 1) * 64;
    const int nw = (wave & 1) * 64;
    const int koff = blockIdx.z * Kloop;
    C += (size_t)blockIdx.z * czoff;

    f32x4_t acc[4][4] = {};

    const int g0 = wave * 2;
    const int rA = g0 * 16 + (lane >> 2);
    const int kk = (lane & 3) * 8;

    const __bf16* gA0 = A + (size_t)(m0 + rA) * lda + kk + koff;
    const __bf16* gA1 = gA0 + (size_t)16 * lda;
    const __bf16* gB0 = W + (size_t)(n0 + rA) * ldw + kk + koff;
    const __bf16* gB1 = gB0 + (size_t)16 * ldw;

    __bf16* lA0 = &As[(size_t)g0 * 512];
    __bf16* lA1 = &As[(size_t)(g0 + 1) * 512];
    __bf16* lB0 = &Bs[(size_t)g0 * 512];
    __bf16* lB1 = &Bs[(size_t)(g0 + 1) * 512];

    const int fr = lane & 15;
    const int fk = (lane >> 4) * 8;

    for (int k0 = 0; k0 < Kloop; k0 += KSTEP) {
#pragma unroll
        for (int p = 0; p < KSTEP / 32; p++) {
            const int kp = k0 + p * 32;
            const int lp = p * 4096;   // panel offset (elements)
            __builtin_amdgcn_global_load_lds(
                (const __attribute__((address_space(1))) void*)(gA0 + kp),
                (__attribute__((address_space(3))) void*)(lA0 + lp), 16, 0, 0);
            __builtin_amdgcn_global_load_lds(
                (const __attribute__((address_space(1))) void*)(gA1 + kp),
                (__attribute__((address_space(3))) void*)(lA1 + lp), 16, 0, 0);
            __builtin_amdgcn_global_load_lds(
                (const __attribute__((address_space(1))) void*)(gB0 + kp),
                (__attribute__((address_space(3))) void*)(lB0 + lp), 16, 0, 0);
            __builtin_amdgcn_global_load_lds(
                (const __attribute__((address_space(1))) void*)(gB1 + kp),
                (__attribute__((address_space(3))) void*)(lB1 + lp), 16, 0, 0);
        }
        __syncthreads();

#pragma unroll
        for (int p = 0; p < KSTEP / 32; p++) {
            const int lp = p * 4096;
            bf16x8_t av[4], bv[4];
#pragma unroll
            for (int mt = 0; mt < 4; mt++)
                av[mt] = *(const bf16x8_t*)&As[lp + (mw + mt * 16 + fr) * 32 + fk];
#pragma unroll
            for (int nt = 0; nt < 4; nt++)
                bv[nt] = *(const bf16x8_t*)&Bs[lp + (nw + nt * 16 + fr) * 32 + fk];

#pragma unroll
            for (int mt = 0; mt < 4; mt++)
#pragma unroll
                for (int nt = 0; nt < 4; nt++)
                    acc[mt][nt] = __builtin_amdgcn_mfma_f32_16x16x32_bf16(
                        av[mt], bv[nt], acc[mt][nt], 0, 0, 0);
        }
        __syncthreads();
    }

    const int cn = n0 + nw + (lane & 15);
    const int rb = m0 + mw + (lane >> 4) * 4;
#pragma unroll
    for (int mt = 0; mt < 4; mt++)
#pragma unroll
        for (int nt = 0; nt < 4; nt++) {
            const int n = cn + nt * 16;
            if (n >= Nmax) continue;
#pragma unroll
            for (int r = 0; r < 4; r++) {
                float v = acc[mt][nt][r];
                OutT* p = &C[(size_t)(rb + mt * 16 + r) * ldc + n];
                if (EPI == 1) {
                    v += bias[n];
                    v = (v > 20.f) ? v : __logf(1.f + __expf(v));
                    *p = (OutT)v;
                } else if (EPI == 2) {
                    atomicAdd((float*)p, v);
                } else {
                    *p = (OutT)v;
                }
            }
        }
}

// ---------------------------------------------------------------------------
// dt_proj GEMM with inlined fp32->bf16 A staging.
// deltaT[(b*4096+d)*1024+t] = bf16(softplus(dbc[:,0:128] @ wdt16^T + bias))
// -- TRANSPOSED output (t-major per d) so the scan can vector-load over t.
// ---------------------------------------------------------------------------
__global__ __launch_bounds__(256) void gemm_dt(
    const float* __restrict__ A,      // dbc (ld 160)
    const __bf16* __restrict__ W,     // wdt16 (4096,128)
    __bf16* __restrict__ C,           // deltaT ((b*4096+d)*1024+t)
    const float* __restrict__ bias)
{
    __shared__ __bf16 As[4 * 64 * 32];   // [panel][row][32]
    __shared__ __bf16 Bs[4 * 64 * 32];

    const int tid  = threadIdx.x;
    const int wave = tid >> 6;
    const int lane = tid & 63;
    const int m0 = blockIdx.y * 64;
    const int n0 = blockIdx.x * 64;
    const int mw = (wave >> 1) * 32;
    const int nw = (wave & 1) * 32;

    {
        const int r  = tid >> 2;          // 0..63
        const int cg = (tid & 3) * 8;     // 0,8,16,24
        const float* gA = A + (size_t)(m0 + r) * 160 + cg;
#pragma unroll
        for (int p = 0; p < 4; p++) {
            const float4 f0 = *(const float4*)(gA + p * 32);
            const float4 f1 = *(const float4*)(gA + p * 32 + 4);
            bf16x8_t v;
            v[0] = (__bf16)f0.x; v[1] = (__bf16)f0.y; v[2] = (__bf16)f0.z; v[3] = (__bf16)f0.w;
            v[4] = (__bf16)f1.x; v[5] = (__bf16)f1.y; v[6] = (__bf16)f1.z; v[7] = (__bf16)f1.w;
            *(bf16x8_t*)&As[p * 2048 + r * 32 + cg] = v;
        }
    }
    {
        const int rB = wave * 16 + (lane >> 2);
        const int kk = (lane & 3) * 8;
        const __bf16* gB = W + (size_t)(n0 + rB) * 128 + kk;
        __bf16* lB = &Bs[wave * 512];
#pragma unroll
        for (int p = 0; p < 4; p++) {
            __builtin_amdgcn_global_load_lds(
                (const __attribute__((address_space(1))) void*)(gB + p * 32),
                (__attribute__((address_space(3))) void*)(lB + p * 2048), 16, 0, 0);
        }
    }
    __syncthreads();

    const int fr = lane & 15;
    const int fk = (lane >> 4) * 8;
    f32x4_t acc[2][2] = {};
#pragma unroll
    for (int p = 0; p < 4; p++) {
        bf16x8_t av[2], bv[2];
#pragma unroll
        for (int mt = 0; mt < 2; mt++)
            av[mt] = *(const bf16x8_t*)&As[p * 2048 + (mw + mt * 16 + fr) * 32 + fk];
#pragma unroll
        for (int nt = 0; nt < 2; nt++)
            bv[nt] = *(const bf16x8_t*)&Bs[p * 2048 + (nw + nt * 16 + fr) * 32 + fk];
#pragma unroll
        for (int mt = 0; mt < 2; mt++)
#pragma unroll
            for (int nt = 0; nt < 2; nt++)
                acc[mt][nt] = __builtin_amdgcn_mfma_f32_16x16x32_bf16(
                    av[mt], bv[nt], acc[mt][nt], 0, 0, 0);
    }

    // C/D layout: col = lane&15, row = (lane>>4)*4 + reg.  Row m = b*1024+t;
    // 4 consecutive regs = 4 consecutive t.
    const int cn = n0 + nw + (lane & 15);
    const int rb = m0 + mw + (lane >> 4) * 4;
#pragma unroll
    for (int mt = 0; mt < 2; mt++)
#pragma unroll
        for (int nt = 0; nt < 2; nt++) {
            const int n = cn + nt * 16;
            const float bs = bias[n];
            bf16x4_t pk;
#pragma unroll
            for (int r = 0; r < 4; r++) {
                float v = acc[mt][nt][r] + bs;
                v = (v > 20.f) ? v : __logf(1.f + __expf(v));
                pk[r] = (__bf16)v;
            }
            const int m  = rb + mt * 16;
            const int bb = m >> 10;
            const int tt = m & 1023;
            *(bf16x4_t*)&C[((size_t)(bb * 4096 + n)) * 1024 + tt] = pk;
        }
}

// ---------------------------------------------------------------------------
// Causal depthwise conv (width 4) + bias + silu.  64d x 64t tile per block,
// 256 threads; xsT/zT writes via LDS transpose (coalesced 128B t-runs).
// ---------------------------------------------------------------------------
__global__ __launch_bounds__(256) void conv_silu(
    const __bf16* __restrict__ xz16,
    const float* __restrict__ conv_cache,
    const float* __restrict__ conv_w,
    const float* __restrict__ conv_b,
    __bf16* __restrict__ xs16,
    __bf16* __restrict__ xsT,
    __bf16* __restrict__ zT,
    float* __restrict__ cc_out)
{
    __shared__ __bf16 Lxs[64][72];
    __shared__ __bf16 Lz[64][72];

    const int b  = blockIdx.z;
    const int D0 = blockIdx.y * 64;
    const int T0 = blockIdx.x * 64;
    const int dl = threadIdx.x & 63;
    const int tc = threadIdx.x >> 6;     // 0..3
    const int d  = D0 + dl;
    const int t0 = T0 + tc * TC;

    const float4 w  = *(const float4*)&conv_w[d * 4];
    const float bias = conv_b[d];

    float v[TC + 3];
    if (t0 == 0) {
        v[0] = conv_cache[(b * D_INNER + d) * 3 + 0];
        v[1] = conv_cache[(b * D_INNER + d) * 3 + 1];
        v[2] = conv_cache[(b * D_INNER + d) * 3 + 2];
    } else {
        v[0] = (float)xz16[(size_t)(b * TT + t0 - 3) * 8192 + d];
        v[1] = (float)xz16[(size_t)(b * TT + t0 - 2) * 8192 + d];
        v[2] = (float)xz16[(size_t)(b * TT + t0 - 1) * 8192 + d];
    }
#pragma unroll
    for (int k = 0; k < TC; k++)
        v[k + 3] = (float)xz16[(size_t)(b * TT + t0 + k) * 8192 + d];

#pragma unroll
    for (int k = 0; k < TC; k++) {
        float c = v[k] * w.x + v[k + 1] * w.y + v[k + 2] * w.z + v[k + 3] * w.w + bias;
        float s = c / (1.f + __expf(-c));
        xs16[(size_t)(b * TT + t0 + k) * 4096 + d] = (__bf16)s;
        Lxs[dl][tc * TC + k] = (__bf16)s;
    }
#pragma unroll
    for (int k = 0; k < TC; k++)
        Lz[dl][tc * TC + k] = xz16[(size_t)(b * TT + t0 + k) * 8192 + 4096 + d];

    if (t0 + TC == TT) {
        cc_out[(b * D_INNER + d) * 3 + 0] = v[TC];
        cc_out[(b * D_INNER + d) * 3 + 1] = v[TC + 1];
        cc_out[(b * D_INNER + d) * 3 + 2] = v[TC + 2];
    }

    __syncthreads();

    const int d2 = threadIdx.x >> 2;
    const int tq = (threadIdx.x & 3) * 16;
    const size_t to = ((size_t)(b * 4096 + D0 + d2)) * 1024 + T0 + tq;
    *(bf16x8_t*)&xsT[to]     = *(const bf16x8_t*)&Lxs[d2][tq];
    *(bf16x8_t*)&xsT[to + 8] = *(const bf16x8_t*)&Lxs[d2][tq + 8];
    *(bf16x8_t*)&zT[to]      = *(const bf16x8_t*)&Lz[d2][tq];
    *(bf16x8_t*)&zT[to + 8]  = *(const bf16x8_t*)&Lz[d2][tq + 8];
}

// ---------------------------------------------------------------------------
// Chunked selective scan.  P/S layout: ((b*NC+c)*4096+d)*16+n.
// phase A: per-chunk local scan (P = chunk decay, S = local state).
// scan_prefix: serial combine over the 16 chunks -> Hstart (chunk-start
// states) + h_out.  Removes the O(c) h-combine loop (avg 7.5 iters x 32 B
// x 524K threads ~ 126 MB L2 + serial chain) from phase C.
// phase C: loads its start state with ONE float4 from Hstart.
// ---------------------------------------------------------------------------
__global__ __launch_bounds__(256) void scan_phase_a(
    const __bf16* __restrict__ deltaT,   // (b*4096+d)*1024+t
    const float* __restrict__ dbc,       // (2048,160): B at 128
    const __bf16* __restrict__ xsT,      // (b*4096+d)*1024+t
    const float* __restrict__ A_log,
    float* __restrict__ P,
    float* __restrict__ S)
{
    __shared__ float Lb[CL][16];         // B slice for this (b,c): 4 KB

    const int idx = blockIdx.x * 256 + threadIdx.x;
    const int sub = idx & 3;
    const int d   = (idx >> 2) & 4095;
    const int c   = (idx >> 14) & (NC - 1);   // block-uniform
    const int b   = idx >> 18;                // block-uniform

    // cooperative B stage: 256 threads x 1 float4 = 64 t x 16 floats
    {
        const int r = threadIdx.x >> 2;
        const int q = (threadIdx.x & 3) * 4;
        const float* g = dbc + ((size_t)b * TT + c * CL + r) * 160 + 128 + q;
        *(float4*)&Lb[r][q] = *(const float4*)g;
    }
    __syncthreads();

    const float4 Af = *(const float4*)&A_log[d * 16 + sub * 4];
    const float Ad0 = -__expf(Af.x), Ad1 = -__expf(Af.y);
    const float Ad2 = -__expf(Af.z), Ad3 = -__expf(Af.w);

    const size_t tb = ((size_t)(b * 4096 + d)) * 1024 + c * CL;
    const __bf16* pdT = deltaT + tb;
    const __bf16* pxT = xsT + tb;

    float h0 = 0.f, h1 = 0.f, h2 = 0.f, h3 = 0.f, sd = 0.f;
    for (int to = 0; to < CL; to += 8) {
        const bf16x8_t dv = *(const bf16x8_t*)&pdT[to];
        const bf16x8_t xv = *(const bf16x8_t*)&pxT[to];
#pragma unroll
        for (int k = 0; k < 8; k++) {
            const float delta = (float)dv[k];
            const float x     = (float)xv[k];
            const float4 Bv   = *(const float4*)&Lb[to + k][sub * 4];
            const float dx = delta * x;
            h0 = __expf(delta * Ad0) * h0 + dx * Bv.x;
            h1 = __expf(delta * Ad1) * h1 + dx * Bv.y;
            h2 = __expf(delta * Ad2) * h2 + dx * Bv.z;
            h3 = __expf(delta * Ad3) * h3 + dx * Bv.w;
            sd += delta;
        }
    }
    const size_t o = ((size_t)(b * NC + c) * 4096 + d) * 16 + sub * 4;
    *(float4*)&P[o] = make_float4(__expf(Ad0 * sd), __expf(Ad1 * sd),
                                  __expf(Ad2 * sd), __expf(Ad3 * sd));
    *(float4*)&S[o] = make_float4(h0, h1, h2, h3);
}

// scan_prefix: thread per (b,d,sub) = 32768 threads = 128 blocks.
// Hstart[b,c,d,:] = state entering chunk c; h_out = state after chunk 15.
__global__ __launch_bounds__(256) void scan_prefix(
    const float* __restrict__ P, const float* __restrict__ S,
    const float* __restrict__ h_in,
    float* __restrict__ Hstart, float* __restrict__ h_out)
{
    const int idx = blockIdx.x * 256 + threadIdx.x;
    const int sub = idx & 3;
    const int d   = (idx >> 2) & 4095;
    const int b   = idx >> 14;

    const size_t hb = ((size_t)b * 4096 + d) * 16 + sub * 4;
    float4 h = *(const float4*)&h_in[hb];
#pragma unroll
    for (int c = 0; c < NC; c++) {
        const size_t o = ((size_t)(b * NC + c) * 4096 + d) * 16 + sub * 4;
        *(float4*)&Hstart[o] = h;
        const float4 p = *(const float4*)&P[o];
        const float4 s = *(const float4*)&S[o];
        h.x = p.x * h.x + s.x;
        h.y = p.y * h.y + s.y;
        h.z = p.z * h.z + s.z;
        h.w = p.w * h.w + s.w;
    }
    *(float4*)&h_out[hb] = h;
}

__global__ __launch_bounds__(256) void scan_phase_c(
    const __bf16* __restrict__ deltaT,
    const __bf16* __restrict__ zT,       // t-major z
    const float* __restrict__ dbc,       // B at 128, C at 144
    const __bf16* __restrict__ xsT,
    const float* __restrict__ Hstart,    // chunk-start states
    const float* __restrict__ A_log,
    const float* __restrict__ D_param,
    __bf16* __restrict__ ys16)
{
    __shared__ float Lbc[CL][32];        // B|C slice for this (b,c): 8 KB

    const int idx = blockIdx.x * 256 + threadIdx.x;
    const int sub = idx & 3;
    const int d   = (idx >> 2) & 4095;
    const int c   = (idx >> 14) & (NC - 1);   // block-uniform
    const int b   = idx >> 18;                // block-uniform

    // cooperative B|C stage: 256 threads x 2 float4 = 64 t x 32 floats
    {
        const int r = threadIdx.x >> 2;
        const int q = (threadIdx.x & 3) * 8;
        const float* g = dbc + ((size_t)b * TT + c * CL + r) * 160 + 128 + q;
        *(float4*)&Lbc[r][q]     = *(const float4*)g;
        *(float4*)&Lbc[r][q + 4] = *(const float4*)(g + 4);
    }
    __syncthreads();

    const float4 Af = *(const float4*)&A_log[d * 16 + sub * 4];
    const float Ad0 = -__expf(Af.x), Ad1 = -__expf(Af.y);
    const float Ad2 = -__expf(Af.z), Ad3 = -__expf(Af.w);
    const float Dp = D_param[d];

    // chunk-start state: ONE float4 (combine loop moved to scan_prefix)
    const float4 hf = *(const float4*)
        &Hstart[((size_t)(b * NC + c) * 4096 + d) * 16 + sub * 4];
    float h0 = hf.x, h1 = hf.y, h2 = hf.z, h3 = hf.w;

    const size_t tb = ((size_t)(b * 4096 + d)) * 1024 + c * CL;
    const __bf16* pdT = deltaT + tb;
    const __bf16* pxT = xsT + tb;
    const __bf16* pzT = zT + tb;
    __bf16* py = ys16 + ((size_t)b * TT + c * CL) * 4096 + d;

    for (int to = 0; to < CL; to += 8) {
        const bf16x8_t dv  = *(const bf16x8_t*)&pdT[to];
        const bf16x8_t xv8 = *(const bf16x8_t*)&pxT[to];
        const bf16x8_t zv8 = *(const bf16x8_t*)&pzT[to];
#pragma unroll
        for (int k = 0; k < 8; k++) {
            const float delta = (float)dv[k];
            const float x     = (float)xv8[k];
            const float4 Bv   = *(const float4*)&Lbc[to + k][sub * 4];
            const float4 Cv   = *(const float4*)&Lbc[to + k][16 + sub * 4];
            const float dx = delta * x;

            h0 = __expf(delta * Ad0) * h0 + dx * Bv.x;
            h1 = __expf(delta * Ad1) * h1 + dx * Bv.y;
            h2 = __expf(delta * Ad2) * h2 + dx * Bv.z;
            h3 = __expf(delta * Ad3) * h3 + dx * Bv.w;

            float y = h0 * Cv.x + h1 * Cv.y + h2 * Cv.z + h3 * Cv.w;
            y += __shfl_xor(y, 1);
            y += __shfl_xor(y, 2);

            if (sub == 0) {
                const float zv = (float)zv8[k];
                y += Dp * x;
                const float g = zv / (1.f + __expf(-zv));
                py[(size_t)(to + k) * 4096] = (__bf16)(y * g);
            }
        }
    }
}

// ---------------------------------------------------------------------------
extern "C" void kernel_launch(void* const* d_in, const int* in_sizes, int n_in,
                              void* d_out, int out_size, void* d_ws, size_t ws_size,
                              hipStream_t stream)
{
    const float* x          = (const float*)d_in[0];
    const float* h_in       = (const float*)d_in[1];
    const float* conv_cache = (const float*)d_in[2];
    const float* in_proj_w  = (const float*)d_in[3];
    const float* conv_w     = (const float*)d_in[4];
    const float* conv_b     = (const float*)d_in[5];
    const float* x_proj_w   = (const float*)d_in[6];
    const float* dt_proj_w  = (const float*)d_in[7];
    const float* dt_proj_b  = (const float*)d_in[8];
    const float* A_log      = (const float*)d_in[9];
    const float* D_param    = (const float*)d_in[10];
    const float* out_proj_w = (const float*)d_in[11];

    float* out    = (float*)d_out;
    float* h_out  = (float*)d_out + (size_t)NB * TT * D_MODEL;
    float* cc_out = h_out + (size_t)NB * D_INNER * D_STATE;

    char* ws = (char*)d_ws;
    // Lifetime-overlaid workspace map (peak 121.9 MB):
    // [0, 33.5M)        xz16 (in_proj out; conv reads)
    //                   -> after conv:   Pbuf [0,8.4M) + Sbuf [8.4M,16.8M)
    //                                    + Hstart [16.8M,25.2M)
    //                   -> after scan_c: Pout (2x16.8M fp32 partials)
    // [33.5M, 67.1M)    wi16 (in_proj weight)
    //                   -> after in_proj: xsT [33.5M,50.3M) + zT [50.3M,67.1M)
    // [67.1M, 83.9M)    x16 [67.1M,75.5M) (in_proj A)
    //                   -> after in_proj: deltaT (16.8M)
    // [83.9M, 100.7M)   wo16
    // [100.7M, 117.4M)  xs16 (conv out, x_proj A; dead after x_proj)
    //                   -> ys16 (scan_c out) aliases it
    // [117.4M, 119.5M)  wx16 (256x4096 padded)
    // [119.5M, 120.5M)  wdt16 (4096x128)
    // [120.5M, 121.9M)  dbc fp32 (2048x160)
    __bf16* xz16    = (__bf16*)(ws);
    float*  Pbuf    = (float*)(ws);
    float*  Sbuf    = (float*)(ws + 8388608);
    float*  Hstart  = (float*)(ws + 16777216);
    float*  Pout    = (float*)(ws);
    __bf16* wi16    = (__bf16*)(ws + 33554432);
    __bf16* xsT     = (__bf16*)(ws + 33554432);
    __bf16* zT      = (__bf16*)(ws + 50331648);
    __bf16* x16     = (__bf16*)(ws + 67108864);
    __bf16* deltaT  = (__bf16*)(ws + 67108864);
    __bf16* wo16    = (__bf16*)(ws + 83886080);
    __bf16* xs16    = (__bf16*)(ws + 100663296);
    __bf16* ys16    = (__bf16*)(ws + 100663296);  // aliases xs16 (dead after x_proj)
    __bf16* wx16    = (__bf16*)(ws + 117440512);
    __bf16* wdt16   = (__bf16*)(ws + 119537664);
    float*  dbc     = (float*)(ws + 120586240);

    dim3 blk(256);
    const size_t NOUT = (size_t)2048 * 2048;

    // 0) all casts + zero-inits (wx pad, dbc) in ONE dispatch
    fused_cast<<<dim3(15424), blk, 0, stream>>>(
        x, in_proj_w, out_proj_w, x_proj_w, dt_proj_w,
        x16, wi16, wo16, wx16, wdt16, (__bf16*)dbc);

    // 1) xz16 = x @ in_proj_w^T  (M=2048, N=8192, K=2048)
    gemm_bf16_256<<<dim3(32, 8), dim3(512), 0, stream>>>(
        x16, 2048, wi16, 2048, xz16, 8192, 2048 / 32);

    // 2) conv + silu -> xs16 (row-major) + xsT/zT (t-major), new_conv_cache
    conv_silu<<<dim3(TT / 64, D_INNER / 64, NB), blk, 0, stream>>>(
        xz16, conv_cache, conv_w, conv_b, xs16, xsT, zT, cc_out);

    // 3) dbc = xs @ x_proj_w^T  (split-K=16, KSTEP=64, atomic; N=160 guarded)
    gemm_bf16_nt<2, 64, float><<<dim3(2, 16, 16), blk, 0, stream>>>(
        xs16, 4096, wx16, 4096, dbc, 160, 256, 160, nullptr, 0);

    // 4) deltaT = bf16(softplus(dbc[:, :128] @ dt_proj_w^T + b)), t-major
    gemm_dt<<<dim3(64, 32), blk, 0, stream>>>(dbc, wdt16, deltaT, dt_proj_b);

    // 5) chunked selective scan: local scans -> chunk prefix -> apply
    scan_phase_a<<<dim3(NB * D_INNER * NC * 4 / 256), blk, 0, stream>>>(
        deltaT, dbc, xsT, A_log, Pbuf, Sbuf);
    scan_prefix<<<dim3(NB * D_INNER * 4 / 256), blk, 0, stream>>>(
        Pbuf, Sbuf, h_in, Hstart, h_out);
    scan_phase_c<<<dim3(NB * D_INNER * NC * 4 / 256), blk, 0, stream>>>(
        deltaT, zT, dbc, xsT, Hstart, A_log, D_param, ys16);

    // 6) out = ys @ out_proj_w^T  (split-K=2 into disjoint fp32 partials)
    gemm_bf16_nt<0, 64, float><<<dim3(16, 16, 2), blk, 0, stream>>>(
        ys16, 4096, wo16, 4096, Pout, 2048, 2048, 2048, nullptr, NOUT);
    reduce_out<<<dim3(4096), blk, 0, stream>>>(
        (const float4*)Pout, (const float4*)(Pout + NOUT), (float4*)out);
}

// Round 13
// 418.910 us; speedup vs baseline: 1.0099x; 1.0099x over previous
//
#include <hip/hip_runtime.h>
#include <hip/hip_bf16.h>
#include <math.h>

#define D_MODEL 2048
#define D_INNER 4096
#define D_STATE 16
#define D_CONV  4
#define DT_RANK 128
#define NB      2
#define TT      1024
#define M_TOT   (NB * TT)          // 2048 rows for all GEMMs
#define NC      16                 // scan chunks
#define CL      64                 // chunk length (TT/NC)
#define TC      16                 // conv t-chunk

typedef __bf16 bf16x8_t __attribute__((ext_vector_type(8)));
typedef __bf16 bf16x4_t __attribute__((ext_vector_type(4)));
typedef float  f32x4_t  __attribute__((ext_vector_type(4)));

// ---------------------------------------------------------------------------
// Fused cast/zero kernel (unchanged).
// ---------------------------------------------------------------------------
__global__ __launch_bounds__(256) void fused_cast(
    const float* __restrict__ x,  const float* __restrict__ wi,
    const float* __restrict__ wo, const float* __restrict__ wx,
    const float* __restrict__ wdt,
    __bf16* __restrict__ x16,  __bf16* __restrict__ wi16,
    __bf16* __restrict__ wo16, __bf16* __restrict__ wx16,
    __bf16* __restrict__ wdt16, __bf16* __restrict__ dbc16)
{
    const size_t g = (size_t)blockIdx.x * 256 + threadIdx.x;
    const float* src; __bf16* dst; size_t off;
    if      (g < 524288)  { src = x;   dst = x16;   off = g; }
    else if (g < 2621440) { src = wi;  dst = wi16;  off = g - 524288; }
    else if (g < 3670016) { src = wo;  dst = wo16;  off = g - 2621440; }
    else if (g < 3801088) { off = g - 3670016; dst = wx16;
                            src = (g < 3751936) ? wx : nullptr; }
    else if (g < 3866624) { src = wdt; dst = wdt16; off = g - 3801088; }
    else                  { src = nullptr; dst = dbc16; off = g - 3866624; }

    bf16x8_t v;
    if (src) {
        const float4 f0 = ((const float4*)src)[2 * off];
        const float4 f1 = ((const float4*)src)[2 * off + 1];
        v[0] = (__bf16)f0.x; v[1] = (__bf16)f0.y; v[2] = (__bf16)f0.z; v[3] = (__bf16)f0.w;
        v[4] = (__bf16)f1.x; v[5] = (__bf16)f1.y; v[6] = (__bf16)f1.z; v[7] = (__bf16)f1.w;
    } else {
        v = (bf16x8_t)(__bf16)0.f;   // bit pattern 0 == fp32 0.0 for zeroed fp32 dst
    }
    ((bf16x8_t*)dst)[off] = v;
}

// ---------------------------------------------------------------------------
// out = P0 + P1 elementwise (split-K reduction, fp32, float4-vectorized).
// ---------------------------------------------------------------------------
__global__ __launch_bounds__(256) void reduce_out(
    const float4* __restrict__ p0, const float4* __restrict__ p1,
    float4* __restrict__ o)
{
    const size_t g = (size_t)blockIdx.x * 256 + threadIdx.x;
    const float4 a = p0[g];
    const float4 b = p1[g];
    o[g] = make_float4(a.x + b.x, a.y + b.y, a.z + b.z, a.w + b.w);
}

// ---------------------------------------------------------------------------
// 256x256-tile bf16 MFMA GEMM, 512 threads (8 waves as 2M x 4N), BK=32,
// 4-deep LDS ring buffer, counted-vmcnt pipeline, setprio around MFMA,
// XOR slot-swizzled LDS (0 bank conflicts, verified R4-R12).
// Structural ceiling accepted (R8 cross-phase, R9 2-blk/CU variants null):
// LDS-read (~1536 cyc/tile/CU) + MFMA (~1242) serialize under barrier
// lockstep -> ~900 TF at this geometry.  Best measured schedule.
// C = A(M,K;lda) @ W(N,K;ldw)^T, bf16 out.  Requires K % 32 == 0.
// ---------------------------------------------------------------------------
__global__ __launch_bounds__(512, 2) void gemm_bf16_256(
    const __bf16* __restrict__ A, int lda,
    const __bf16* __restrict__ W, int ldw,
    __bf16* __restrict__ C, int ldc,
    int nt)                              // number of BK=32 K-tiles
{
    __shared__ __bf16 As[4 * 128 * 64];
    __shared__ __bf16 Bs[4 * 128 * 64];

    const int tid = threadIdx.x;
    const int w   = tid >> 6;
    const int l   = tid & 63;
    const int m0  = blockIdx.y * 256;
    const int n0  = blockIdx.x * 256;
    const int wm  = (w >> 2) * 128;      // wave M offset
    const int wn  = (w & 3) * 64;        // wave N offset

    const int sl   = ((l & 7) ^ (l >> 3)) & 7;
    const int srow = 2 * (w * 16 + (l >> 3)) + (sl >> 2);
    const int scol = (sl & 3) * 8;
    const __bf16* gA = A + (size_t)(m0 + srow) * lda + scol;
    const __bf16* gB = W + (size_t)(n0 + srow) * ldw + scol;
    __bf16* lA = &As[(size_t)w * 1024];  // wave-uniform LDS bases (elems)
    __bf16* lB = &Bs[(size_t)w * 1024];

    const int fr  = l & 15;
    const int swz = ((((fr & 1) * 4) + (l >> 4)) ^ ((fr >> 1) & 7)) * 8;
    const int aoff = wm * 32 + (fr >> 1) * 64 + swz;
    const int boff = wn * 32 + (fr >> 1) * 64 + swz;

    f32x4_t acc[8][4] = {};

#define STAGE_A(t, q) { \
    const __bf16* s0_ = gA + (size_t)(t) * 32; \
    __builtin_amdgcn_global_load_lds((const __attribute__((address_space(1))) void*)s0_, \
        (__attribute__((address_space(3))) void*)(lA + (q) * 8192), 16, 0, 0); \
    __builtin_amdgcn_global_load_lds((const __attribute__((address_space(1))) void*)(s0_ + (size_t)16 * lda), \
        (__attribute__((address_space(3))) void*)(lA + (q) * 8192 + 512), 16, 0, 0); }
#define STAGE_B(t, q) { \
    const __bf16* s0_ = gB + (size_t)(t) * 32; \
    __builtin_amdgcn_global_load_lds((const __attribute__((address_space(1))) void*)s0_, \
        (__attribute__((address_space(3))) void*)(lB + (q) * 8192), 16, 0, 0); \
    __builtin_amdgcn_global_load_lds((const __attribute__((address_space(1))) void*)(s0_ + (size_t)16 * ldw), \
        (__attribute__((address_space(3))) void*)(lB + (q) * 8192 + 512), 16, 0, 0); }

    STAGE_A(0, 0); STAGE_B(0, 0);
    STAGE_A(1, 1); STAGE_B(1, 1);
    asm volatile("s_waitcnt vmcnt(4)" ::: "memory");
    __builtin_amdgcn_s_barrier();

    for (int t = 0; t < nt; ++t) {
        const int q  = t & 3;
        const int qn = (t + 2) & 3;
        const __bf16* Aq = &As[q * 8192];
        const __bf16* Bq = &Bs[q * 8192];
        bf16x8_t av[4], bv[4];

#pragma unroll
        for (int i = 0; i < 4; i++)
            av[i] = *(const bf16x8_t*)&Aq[aoff + i * 512];
#pragma unroll
        for (int i = 0; i < 4; i++)
            bv[i] = *(const bf16x8_t*)&Bq[boff + i * 512];
        if (t + 2 < nt) STAGE_A(t + 2, qn);
        __builtin_amdgcn_s_barrier();
        asm volatile("s_waitcnt lgkmcnt(0)" ::: "memory");
        __builtin_amdgcn_sched_barrier(0);
        __builtin_amdgcn_s_setprio(1);
#pragma unroll
        for (int mt = 0; mt < 4; mt++)
#pragma unroll
            for (int nn = 0; nn < 4; nn++)
                acc[mt][nn] = __builtin_amdgcn_mfma_f32_16x16x32_bf16(
                    av[mt], bv[nn], acc[mt][nn], 0, 0, 0);
        __builtin_amdgcn_s_setprio(0);
        __builtin_amdgcn_s_barrier();

#pragma unroll
        for (int i = 0; i < 4; i++)
            av[i] = *(const bf16x8_t*)&Aq[aoff + (i + 4) * 512];
        if (t + 2 < nt) STAGE_B(t + 2, qn);
        __builtin_amdgcn_s_barrier();
        asm volatile("s_waitcnt lgkmcnt(0)" ::: "memory");
        __builtin_amdgcn_sched_barrier(0);
        __builtin_amdgcn_s_setprio(1);
#pragma unroll
        for (int mt = 0; mt < 4; mt++)
#pragma unroll
            for (int nn = 0; nn < 4; nn++)
                acc[mt + 4][nn] = __builtin_amdgcn_mfma_f32_16x16x32_bf16(
                    av[mt], bv[nn], acc[mt + 4][nn], 0, 0, 0);
        __builtin_amdgcn_s_setprio(0);
        if (t + 2 < nt) asm volatile("s_waitcnt vmcnt(4)" ::: "memory");
        else            asm volatile("s_waitcnt vmcnt(0)" ::: "memory");
        __builtin_amdgcn_s_barrier();
    }
#undef STAGE_A
#undef STAGE_B

    const int cn = n0 + wn + fr;
    const int rb = m0 + wm + (l >> 4) * 4;
#pragma unroll
    for (int mt = 0; mt < 8; mt++)
#pragma unroll
        for (int nn = 0; nn < 4; nn++)
#pragma unroll
            for (int r = 0; r < 4; r++)
                C[(size_t)(rb + mt * 16 + r) * ldc + cn + nn * 16] =
                    (__bf16)acc[mt][nn][r];
}

// ---------------------------------------------------------------------------
// bf16 MFMA GEMM: C(M,Nmax) OutT (+EPI) = A(M,K;lda) bf16 @ W(N,K;ldw)^T.
// 128x128 tile, 256 threads (4 waves).  Split-K via gridDim.z; czoff = per-z
// C offset (0 -> same C + EPI=2 atomics; >0 -> disjoint partials + EPI=0).
// ---------------------------------------------------------------------------
template <int EPI, int KSTEP, typename OutT>
__global__ __launch_bounds__(256) void gemm_bf16_nt(
    const __bf16* __restrict__ A, int lda,
    const __bf16* __restrict__ W, int ldw,
    OutT* __restrict__ C, int ldc,
    int Kloop, int Nmax, const float* __restrict__ bias, size_t czoff)
{
    __shared__ __bf16 As[128 * KSTEP];
    __shared__ __bf16 Bs[128 * KSTEP];

    const int tid  = threadIdx.x;
    const int wave = tid >> 6;
    const int lane = tid & 63;
    const int m0 = blockIdx.y * 128;
    const int n0 = blockIdx.x * 128;
    const int mw = (wave >> 1) * 64;
    const int nw = (wave & 1) * 64;
    const int koff = blockIdx.z * Kloop;
    C += (size_t)blockIdx.z * czoff;

    f32x4_t acc[4][4] = {};

    const int g0 = wave * 2;
    const int rA = g0 * 16 + (lane >> 2);
    const int kk = (lane & 3) * 8;

    const __bf16* gA0 = A + (size_t)(m0 + rA) * lda + kk + koff;
    const __bf16* gA1 = gA0 + (size_t)16 * lda;
    const __bf16* gB0 = W + (size_t)(n0 + rA) * ldw + kk + koff;
    const __bf16* gB1 = gB0 + (size_t)16 * ldw;

    __bf16* lA0 = &As[(size_t)g0 * 512];
    __bf16* lA1 = &As[(size_t)(g0 + 1) * 512];
    __bf16* lB0 = &Bs[(size_t)g0 * 512];
    __bf16* lB1 = &Bs[(size_t)(g0 + 1) * 512];

    const int fr = lane & 15;
    const int fk = (lane >> 4) * 8;

    for (int k0 = 0; k0 < Kloop; k0 += KSTEP) {
#pragma unroll
        for (int p = 0; p < KSTEP / 32; p++) {
            const int kp = k0 + p * 32;
            const int lp = p * 4096;   // panel offset (elements)
            __builtin_amdgcn_global_load_lds(
                (const __attribute__((address_space(1))) void*)(gA0 + kp),
                (__attribute__((address_space(3))) void*)(lA0 + lp), 16, 0, 0);
            __builtin_amdgcn_global_load_lds(
                (const __attribute__((address_space(1))) void*)(gA1 + kp),
                (__attribute__((address_space(3))) void*)(lA1 + lp), 16, 0, 0);
            __builtin_amdgcn_global_load_lds(
                (const __attribute__((address_space(1))) void*)(gB0 + kp),
                (__attribute__((address_space(3))) void*)(lB0 + lp), 16, 0, 0);
            __builtin_amdgcn_global_load_lds(
                (const __attribute__((address_space(1))) void*)(gB1 + kp),
                (__attribute__((address_space(3))) void*)(lB1 + lp), 16, 0, 0);
        }
        __syncthreads();

#pragma unroll
        for (int p = 0; p < KSTEP / 32; p++) {
            const int lp = p * 4096;
            bf16x8_t av[4], bv[4];
#pragma unroll
            for (int mt = 0; mt < 4; mt++)
                av[mt] = *(const bf16x8_t*)&As[lp + (mw + mt * 16 + fr) * 32 + fk];
#pragma unroll
            for (int nt = 0; nt < 4; nt++)
                bv[nt] = *(const bf16x8_t*)&Bs[lp + (nw + nt * 16 + fr) * 32 + fk];

#pragma unroll
            for (int mt = 0; mt < 4; mt++)
#pragma unroll
                for (int nt = 0; nt < 4; nt++)
                    acc[mt][nt] = __builtin_amdgcn_mfma_f32_16x16x32_bf16(
                        av[mt], bv[nt], acc[mt][nt], 0, 0, 0);
        }
        __syncthreads();
    }

    const int cn = n0 + nw + (lane & 15);
    const int rb = m0 + mw + (lane >> 4) * 4;
#pragma unroll
    for (int mt = 0; mt < 4; mt++)
#pragma unroll
        for (int nt = 0; nt < 4; nt++) {
            const int n = cn + nt * 16;
            if (n >= Nmax) continue;
#pragma unroll
            for (int r = 0; r < 4; r++) {
                float v = acc[mt][nt][r];
                OutT* p = &C[(size_t)(rb + mt * 16 + r) * ldc + n];
                if (EPI == 1) {
                    v += bias[n];
                    v = (v > 20.f) ? v : __logf(1.f + __expf(v));
                    *p = (OutT)v;
                } else if (EPI == 2) {
                    atomicAdd((float*)p, v);
                } else {
                    *p = (OutT)v;
                }
            }
        }
}

// ---------------------------------------------------------------------------
// dt_proj GEMM with inlined fp32->bf16 A staging.
// deltaT[(b*4096+d)*1024+t] = bf16(softplus(dbc[:,0:128] @ wdt16^T + bias))
// -- TRANSPOSED output (t-major per d) so the scan can vector-load over t.
// ---------------------------------------------------------------------------
__global__ __launch_bounds__(256) void gemm_dt(
    const float* __restrict__ A,      // dbc (ld 160)
    const __bf16* __restrict__ W,     // wdt16 (4096,128)
    __bf16* __restrict__ C,           // deltaT ((b*4096+d)*1024+t)
    const float* __restrict__ bias)
{
    __shared__ __bf16 As[4 * 64 * 32];   // [panel][row][32]
    __shared__ __bf16 Bs[4 * 64 * 32];

    const int tid  = threadIdx.x;
    const int wave = tid >> 6;
    const int lane = tid & 63;
    const int m0 = blockIdx.y * 64;
    const int n0 = blockIdx.x * 64;
    const int mw = (wave >> 1) * 32;
    const int nw = (wave & 1) * 32;

    {
        const int r  = tid >> 2;          // 0..63
        const int cg = (tid & 3) * 8;     // 0,8,16,24
        const float* gA = A + (size_t)(m0 + r) * 160 + cg;
#pragma unroll
        for (int p = 0; p < 4; p++) {
            const float4 f0 = *(const float4*)(gA + p * 32);
            const float4 f1 = *(const float4*)(gA + p * 32 + 4);
            bf16x8_t v;
            v[0] = (__bf16)f0.x; v[1] = (__bf16)f0.y; v[2] = (__bf16)f0.z; v[3] = (__bf16)f0.w;
            v[4] = (__bf16)f1.x; v[5] = (__bf16)f1.y; v[6] = (__bf16)f1.z; v[7] = (__bf16)f1.w;
            *(bf16x8_t*)&As[p * 2048 + r * 32 + cg] = v;
        }
    }
    {
        const int rB = wave * 16 + (lane >> 2);
        const int kk = (lane & 3) * 8;
        const __bf16* gB = W + (size_t)(n0 + rB) * 128 + kk;
        __bf16* lB = &Bs[wave * 512];
#pragma unroll
        for (int p = 0; p < 4; p++) {
            __builtin_amdgcn_global_load_lds(
                (const __attribute__((address_space(1))) void*)(gB + p * 32),
                (__attribute__((address_space(3))) void*)(lB + p * 2048), 16, 0, 0);
        }
    }
    __syncthreads();

    const int fr = lane & 15;
    const int fk = (lane >> 4) * 8;
    f32x4_t acc[2][2] = {};
#pragma unroll
    for (int p = 0; p < 4; p++) {
        bf16x8_t av[2], bv[2];
#pragma unroll
        for (int mt = 0; mt < 2; mt++)
            av[mt] = *(const bf16x8_t*)&As[p * 2048 + (mw + mt * 16 + fr) * 32 + fk];
#pragma unroll
        for (int nt = 0; nt < 2; nt++)
            bv[nt] = *(const bf16x8_t*)&Bs[p * 2048 + (nw + nt * 16 + fr) * 32 + fk];
#pragma unroll
        for (int mt = 0; mt < 2; mt++)
#pragma unroll
            for (int nt = 0; nt < 2; nt++)
                acc[mt][nt] = __builtin_amdgcn_mfma_f32_16x16x32_bf16(
                    av[mt], bv[nt], acc[mt][nt], 0, 0, 0);
    }

    // C/D layout: col = lane&15, row = (lane>>4)*4 + reg.  Row m = b*1024+t;
    // 4 consecutive regs = 4 consecutive t.
    const int cn = n0 + nw + (lane & 15);
    const int rb = m0 + mw + (lane >> 4) * 4;
#pragma unroll
    for (int mt = 0; mt < 2; mt++)
#pragma unroll
        for (int nt = 0; nt < 2; nt++) {
            const int n = cn + nt * 16;
            const float bs = bias[n];
            bf16x4_t pk;
#pragma unroll
            for (int r = 0; r < 4; r++) {
                float v = acc[mt][nt][r] + bs;
                v = (v > 20.f) ? v : __logf(1.f + __expf(v));
                pk[r] = (__bf16)v;
            }
            const int m  = rb + mt * 16;
            const int bb = m >> 10;
            const int tt = m & 1023;
            *(bf16x4_t*)&C[((size_t)(bb * 4096 + n)) * 1024 + tt] = pk;
        }
}

// ---------------------------------------------------------------------------
// Causal depthwise conv (width 4) + bias + silu.  64d x 64t tile per block,
// 256 threads; xsT/zT writes via LDS transpose (coalesced 128B t-runs).
// ---------------------------------------------------------------------------
__global__ __launch_bounds__(256) void conv_silu(
    const __bf16* __restrict__ xz16,
    const float* __restrict__ conv_cache,
    const float* __restrict__ conv_w,
    const float* __restrict__ conv_b,
    __bf16* __restrict__ xs16,
    __bf16* __restrict__ xsT,
    __bf16* __restrict__ zT,
    float* __restrict__ cc_out)
{
    __shared__ __bf16 Lxs[64][72];
    __shared__ __bf16 Lz[64][72];

    const int b  = blockIdx.z;
    const int D0 = blockIdx.y * 64;
    const int T0 = blockIdx.x * 64;
    const int dl = threadIdx.x & 63;
    const int tc = threadIdx.x >> 6;     // 0..3
    const int d  = D0 + dl;
    const int t0 = T0 + tc * TC;

    const float4 w  = *(const float4*)&conv_w[d * 4];
    const float bias = conv_b[d];

    float v[TC + 3];
    if (t0 == 0) {
        v[0] = conv_cache[(b * D_INNER + d) * 3 + 0];
        v[1] = conv_cache[(b * D_INNER + d) * 3 + 1];
        v[2] = conv_cache[(b * D_INNER + d) * 3 + 2];
    } else {
        v[0] = (float)xz16[(size_t)(b * TT + t0 - 3) * 8192 + d];
        v[1] = (float)xz16[(size_t)(b * TT + t0 - 2) * 8192 + d];
        v[2] = (float)xz16[(size_t)(b * TT + t0 - 1) * 8192 + d];
    }
#pragma unroll
    for (int k = 0; k < TC; k++)
        v[k + 3] = (float)xz16[(size_t)(b * TT + t0 + k) * 8192 + d];

#pragma unroll
    for (int k = 0; k < TC; k++) {
        float c = v[k] * w.x + v[k + 1] * w.y + v[k + 2] * w.z + v[k + 3] * w.w + bias;
        float s = c / (1.f + __expf(-c));
        xs16[(size_t)(b * TT + t0 + k) * 4096 + d] = (__bf16)s;
        Lxs[dl][tc * TC + k] = (__bf16)s;
    }
#pragma unroll
    for (int k = 0; k < TC; k++)
        Lz[dl][tc * TC + k] = xz16[(size_t)(b * TT + t0 + k) * 8192 + 4096 + d];

    if (t0 + TC == TT) {
        cc_out[(b * D_INNER + d) * 3 + 0] = v[TC];
        cc_out[(b * D_INNER + d) * 3 + 1] = v[TC + 1];
        cc_out[(b * D_INNER + d) * 3 + 2] = v[TC + 2];
    }

    __syncthreads();

    const int d2 = threadIdx.x >> 2;
    const int tq = (threadIdx.x & 3) * 16;
    const size_t to = ((size_t)(b * 4096 + D0 + d2)) * 1024 + T0 + tq;
    *(bf16x8_t*)&xsT[to]     = *(const bf16x8_t*)&Lxs[d2][tq];
    *(bf16x8_t*)&xsT[to + 8] = *(const bf16x8_t*)&Lxs[d2][tq + 8];
    *(bf16x8_t*)&zT[to]      = *(const bf16x8_t*)&Lz[d2][tq];
    *(bf16x8_t*)&zT[to + 8]  = *(const bf16x8_t*)&Lz[d2][tq + 8];
}

// ---------------------------------------------------------------------------
// Chunked selective scan (2 phases).  P/S layout: ((b*NC+c)*4096+d)*16+n.
// delta/xs/z consumed in t-major layout via bf16x8 octet loads.
// B (and C) staged in LDS once per block (d-invariant; R11-verified -11 us).
// In-kernel h-combine retained (R12's prefix-split kernel regressed +4 us:
// the combine is latency-hidden under TLP; the extra dispatch + Hstart
// round-trip was pure critical-path cost).
// ---------------------------------------------------------------------------
__global__ __launch_bounds__(256) void scan_phase_a(
    const __bf16* __restrict__ deltaT,   // (b*4096+d)*1024+t
    const float* __restrict__ dbc,       // (2048,160): B at 128
    const __bf16* __restrict__ xsT,      // (b*4096+d)*1024+t
    const float* __restrict__ A_log,
    float* __restrict__ P,
    float* __restrict__ S)
{
    __shared__ float Lb[CL][16];         // B slice for this (b,c): 4 KB

    const int idx = blockIdx.x * 256 + threadIdx.x;
    const int sub = idx & 3;
    const int d   = (idx >> 2) & 4095;
    const int c   = (idx >> 14) & (NC - 1);   // block-uniform
    const int b   = idx >> 18;                // block-uniform

    // cooperative B stage: 256 threads x 1 float4 = 64 t x 16 floats
    {
        const int r = threadIdx.x >> 2;
        const int q = (threadIdx.x & 3) * 4;
        const float* g = dbc + ((size_t)b * TT + c * CL + r) * 160 + 128 + q;
        *(float4*)&Lb[r][q] = *(const float4*)g;
    }
    __syncthreads();

    const float4 Af = *(const float4*)&A_log[d * 16 + sub * 4];
    const float Ad0 = -__expf(Af.x), Ad1 = -__expf(Af.y);
    const float Ad2 = -__expf(Af.z), Ad3 = -__expf(Af.w);

    const size_t tb = ((size_t)(b * 4096 + d)) * 1024 + c * CL;
    const __bf16* pdT = deltaT + tb;
    const __bf16* pxT = xsT + tb;

    float h0 = 0.f, h1 = 0.f, h2 = 0.f, h3 = 0.f, sd = 0.f;
    for (int to = 0; to < CL; to += 8) {
        const bf16x8_t dv = *(const bf16x8_t*)&pdT[to];
        const bf16x8_t xv = *(const bf16x8_t*)&pxT[to];
#pragma unroll
        for (int k = 0; k < 8; k++) {
            const float delta = (float)dv[k];
            const float x     = (float)xv[k];
            const float4 Bv   = *(const float4*)&Lb[to + k][sub * 4];
            const float dx = delta * x;
            h0 = __expf(delta * Ad0) * h0 + dx * Bv.x;
            h1 = __expf(delta * Ad1) * h1 + dx * Bv.y;
            h2 = __expf(delta * Ad2) * h2 + dx * Bv.z;
            h3 = __expf(delta * Ad3) * h3 + dx * Bv.w;
            sd += delta;
        }
    }
    const size_t o = ((size_t)(b * NC + c) * 4096 + d) * 16 + sub * 4;
    *(float4*)&P[o] = make_float4(__expf(Ad0 * sd), __expf(Ad1 * sd),
                                  __expf(Ad2 * sd), __expf(Ad3 * sd));
    *(float4*)&S[o] = make_float4(h0, h1, h2, h3);
}

__global__ __launch_bounds__(256) void scan_phase_c(
    const __bf16* __restrict__ deltaT,
    const __bf16* __restrict__ zT,       // t-major z
    const float* __restrict__ dbc,       // B at 128, C at 144
    const __bf16* __restrict__ xsT,
    const float* __restrict__ P,         // chunk decay
    const float* __restrict__ S,         // chunk local scan
    const float* __restrict__ h_in,
    const float* __restrict__ A_log,
    const float* __restrict__ D_param,
    __bf16* __restrict__ ys16,
    float* __restrict__ h_out)
{
    __shared__ float Lbc[CL][32];        // B|C slice for this (b,c): 8 KB

    const int idx = blockIdx.x * 256 + threadIdx.x;
    const int sub = idx & 3;
    const int d   = (idx >> 2) & 4095;
    const int c   = (idx >> 14) & (NC - 1);   // block-uniform
    const int b   = idx >> 18;                // block-uniform

    // cooperative B|C stage: 256 threads x 2 float4 = 64 t x 32 floats
    {
        const int r = threadIdx.x >> 2;
        const int q = (threadIdx.x & 3) * 8;
        const float* g = dbc + ((size_t)b * TT + c * CL + r) * 160 + 128 + q;
        *(float4*)&Lbc[r][q]     = *(const float4*)g;
        *(float4*)&Lbc[r][q + 4] = *(const float4*)(g + 4);
    }
    __syncthreads();

    const float4 Af = *(const float4*)&A_log[d * 16 + sub * 4];
    const float Ad0 = -__expf(Af.x), Ad1 = -__expf(Af.y);
    const float Ad2 = -__expf(Af.z), Ad3 = -__expf(Af.w);
    const float Dp = D_param[d];

    // h_start = combine(h_in, chunks 0..c-1)
    float4 hf = *(const float4*)&h_in[((size_t)b * 4096 + d) * 16 + sub * 4];
    float h0 = hf.x, h1 = hf.y, h2 = hf.z, h3 = hf.w;
    for (int cc = 0; cc < c; cc++) {
        const size_t o2 = ((size_t)(b * NC + cc) * 4096 + d) * 16 + sub * 4;
        const float4 p = *(const float4*)&P[o2];
        const float4 s = *(const float4*)&S[o2];
        h0 = p.x * h0 + s.x;
        h1 = p.y * h1 + s.y;
        h2 = p.z * h2 + s.z;
        h3 = p.w * h3 + s.w;
    }

    const size_t tb = ((size_t)(b * 4096 + d)) * 1024 + c * CL;
    const __bf16* pdT = deltaT + tb;
    const __bf16* pxT = xsT + tb;
    const __bf16* pzT = zT + tb;
    __bf16* py = ys16 + ((size_t)b * TT + c * CL) * 4096 + d;

    for (int to = 0; to < CL; to += 8) {
        const bf16x8_t dv  = *(const bf16x8_t*)&pdT[to];
        const bf16x8_t xv8 = *(const bf16x8_t*)&pxT[to];
        const bf16x8_t zv8 = *(const bf16x8_t*)&pzT[to];
#pragma unroll
        for (int k = 0; k < 8; k++) {
            const float delta = (float)dv[k];
            const float x     = (float)xv8[k];
            const float4 Bv   = *(const float4*)&Lbc[to + k][sub * 4];
            const float4 Cv   = *(const float4*)&Lbc[to + k][16 + sub * 4];
            const float dx = delta * x;

            h0 = __expf(delta * Ad0) * h0 + dx * Bv.x;
            h1 = __expf(delta * Ad1) * h1 + dx * Bv.y;
            h2 = __expf(delta * Ad2) * h2 + dx * Bv.z;
            h3 = __expf(delta * Ad3) * h3 + dx * Bv.w;

            float y = h0 * Cv.x + h1 * Cv.y + h2 * Cv.z + h3 * Cv.w;
            y += __shfl_xor(y, 1);
            y += __shfl_xor(y, 2);

            if (sub == 0) {
                const float zv = (float)zv8[k];
                y += Dp * x;
                const float g = zv / (1.f + __expf(-zv));
                py[(size_t)(to + k) * 4096] = (__bf16)(y * g);
            }
        }
    }

    if (c == NC - 1) {
        *(float4*)&h_out[((size_t)b * 4096 + d) * 16 + sub * 4] =
            make_float4(h0, h1, h2, h3);
    }
}

// ---------------------------------------------------------------------------
extern "C" void kernel_launch(void* const* d_in, const int* in_sizes, int n_in,
                              void* d_out, int out_size, void* d_ws, size_t ws_size,
                              hipStream_t stream)
{
    const float* x          = (const float*)d_in[0];
    const float* h_in       = (const float*)d_in[1];
    const float* conv_cache = (const float*)d_in[2];
    const float* in_proj_w  = (const float*)d_in[3];
    const float* conv_w     = (const float*)d_in[4];
    const float* conv_b     = (const float*)d_in[5];
    const float* x_proj_w   = (const float*)d_in[6];
    const float* dt_proj_w  = (const float*)d_in[7];
    const float* dt_proj_b  = (const float*)d_in[8];
    const float* A_log      = (const float*)d_in[9];
    const float* D_param    = (const float*)d_in[10];
    const float* out_proj_w = (const float*)d_in[11];

    float* out    = (float*)d_out;
    float* h_out  = (float*)d_out + (size_t)NB * TT * D_MODEL;
    float* cc_out = h_out + (size_t)NB * D_INNER * D_STATE;

    char* ws = (char*)d_ws;
    // Lifetime-overlaid workspace map (peak 121.9 MB):
    // [0, 33.5M)        xz16 (in_proj out; conv reads)
    //                   -> after conv:   Pbuf [0,8.4M) + Sbuf [8.4M,16.8M)
    //                   -> after scan_c: Pout (2x16.8M fp32 partials)
    // [33.5M, 67.1M)    wi16 (in_proj weight)
    //                   -> after in_proj: xsT [33.5M,50.3M) + zT [50.3M,67.1M)
    // [67.1M, 83.9M)    x16 [67.1M,75.5M) (in_proj A)
    //                   -> after in_proj: deltaT (16.8M)
    // [83.9M, 100.7M)   wo16
    // [100.7M, 117.4M)  xs16 (conv out, x_proj A; dead after x_proj)
    //                   -> ys16 (scan_c out) aliases it
    // [117.4M, 119.5M)  wx16 (256x4096 padded)
    // [119.5M, 120.5M)  wdt16 (4096x128)
    // [120.5M, 121.9M)  dbc fp32 (2048x160)
    __bf16* xz16    = (__bf16*)(ws);
    float*  Pbuf    = (float*)(ws);
    float*  Sbuf    = (float*)(ws + 8388608);
    float*  Pout    = (float*)(ws);
    __bf16* wi16    = (__bf16*)(ws + 33554432);
    __bf16* xsT     = (__bf16*)(ws + 33554432);
    __bf16* zT      = (__bf16*)(ws + 50331648);
    __bf16* x16     = (__bf16*)(ws + 67108864);
    __bf16* deltaT  = (__bf16*)(ws + 67108864);
    __bf16* wo16    = (__bf16*)(ws + 83886080);
    __bf16* xs16    = (__bf16*)(ws + 100663296);
    __bf16* ys16    = (__bf16*)(ws + 100663296);  // aliases xs16 (dead after x_proj)
    __bf16* wx16    = (__bf16*)(ws + 117440512);
    __bf16* wdt16   = (__bf16*)(ws + 119537664);
    float*  dbc     = (float*)(ws + 120586240);

    dim3 blk(256);
    const size_t NOUT = (size_t)2048 * 2048;

    // 0) all casts + zero-inits (wx pad, dbc) in ONE dispatch
    fused_cast<<<dim3(15424), blk, 0, stream>>>(
        x, in_proj_w, out_proj_w, x_proj_w, dt_proj_w,
        x16, wi16, wo16, wx16, wdt16, (__bf16*)dbc);

    // 1) xz16 = x @ in_proj_w^T  (M=2048, N=8192, K=2048)
    //    R7-proven 256^2 counted-vmcnt schedule
    gemm_bf16_256<<<dim3(32, 8), dim3(512), 0, stream>>>(
        x16, 2048, wi16, 2048, xz16, 8192, 2048 / 32);

    // 2) conv + silu -> xs16 (row-major) + xsT/zT (t-major), new_conv_cache
    conv_silu<<<dim3(TT / 64, D_INNER / 64, NB), blk, 0, stream>>>(
        xz16, conv_cache, conv_w, conv_b, xs16, xsT, zT, cc_out);

    // 3) dbc = xs @ x_proj_w^T  (split-K=16, KSTEP=64, atomic; N=160 guarded)
    gemm_bf16_nt<2, 64, float><<<dim3(2, 16, 16), blk, 0, stream>>>(
        xs16, 4096, wx16, 4096, dbc, 160, 256, 160, nullptr, 0);

    // 4) deltaT = bf16(softplus(dbc[:, :128] @ dt_proj_w^T + b)), t-major
    gemm_dt<<<dim3(64, 32), blk, 0, stream>>>(dbc, wdt16, deltaT, dt_proj_b);

    // 5) chunked selective scan (2 phases, LDS-staged B/C) -> ys16 + h_out
    scan_phase_a<<<dim3(NB * D_INNER * NC * 4 / 256), blk, 0, stream>>>(
        deltaT, dbc, xsT, A_log, Pbuf, Sbuf);
    scan_phase_c<<<dim3(NB * D_INNER * NC * 4 / 256), blk, 0, stream>>>(
        deltaT, zT, dbc, xsT, Pbuf, Sbuf, h_in, A_log, D_param, ys16, h_out);

    // 6) out = ys @ out_proj_w^T  (split-K=2 into disjoint fp32 partials)
    gemm_bf16_nt<0, 64, float><<<dim3(16, 16, 2), blk, 0, stream>>>(
        ys16, 4096, wo16, 4096, Pout, 2048, 2048, 2048, nullptr, NOUT);
    reduce_out<<<dim3(4096), blk, 0, stream>>>(
        (const float4*)Pout, (const float4*)(Pout + NOUT), (float4*)out);
}